// Round 1
// baseline (1252.687 us; speedup 1.0000x reference)
//
#include <hip/hip_runtime.h>
#include <hip/hip_bf16.h>
#include <math.h>

#define N_   128
#define C_   64
#define T_   256
#define V_   25
#define D_   64
#define CTV  409600   // C*T*V
#define TV   6400     // T*V
#define NT_  32768    // N*T

// ---------------- K1: pooled[n*64+c] = mean over (t,v) ----------------
__global__ __launch_bounds__(256) void k_pool(const float* __restrict__ x0,
                                              float* __restrict__ pooled) {
    const int bid = blockIdx.x;            // n*64 + c  (plane of 6400 contiguous floats)
    const int tid = threadIdx.x;
    const float4* base = (const float4*)(x0 + (size_t)bid * TV);
    float s = 0.f;
    for (int i = tid; i < 1600; i += 256) {
        float4 f = base[i];
        s += (f.x + f.y) + (f.z + f.w);
    }
    #pragma unroll
    for (int off = 32; off > 0; off >>= 1) s += __shfl_down(s, off);
    __shared__ float red[4];
    if ((tid & 63) == 0) red[tid >> 6] = s;
    __syncthreads();
    if (tid == 0) pooled[bid] = (red[0] + red[1] + red[2] + red[3]) * (1.0f / TV);
}

// ---------------- K2: SE gate -> WfT[n][d][c], bfv[n][d]; plus mg/gi precompute ----------------
__global__ __launch_bounds__(256) void k_se(
    const float* __restrict__ pooled, const float* __restrict__ fc1w,
    const float* __restrict__ fc1b,  const float* __restrict__ fc2w,
    const float* __restrict__ fc2b,  const float* __restrict__ Wm,
    const float* __restrict__ bm,    const float* __restrict__ mask,
    const int* __restrict__ shin,    const int* __restrict__ ep,
    float* __restrict__ WfT, float* __restrict__ bfv,
    float* __restrict__ mg,  int* __restrict__ gi)
{
    __shared__ float sp[64], sh[16], sl[4];
    __shared__ float wk[64 * 65];          // W[k] staged [c][d] padded (+1) to kill bank conflicts
    const int tid = threadIdx.x, n = blockIdx.x;
    if (tid < 64) sp[tid] = pooled[n * 64 + tid];
    __syncthreads();
    if (tid < 16) {
        float s = fc1b[tid];
        #pragma unroll
        for (int c = 0; c < 64; c++) s = fmaf(sp[c], fc1w[tid * 64 + c], s);
        sh[tid] = fmaxf(s, 0.f);
    }
    __syncthreads();
    if (tid < 4) {
        float s = fc2b[tid];
        #pragma unroll
        for (int j = 0; j < 16; j++) s = fmaf(sh[j], fc2w[tid * 16 + j], s);
        sl[tid] = s;
    }
    __syncthreads();
    const int e = ep[0];
    const float tao = (e >= 60) ? 1.0f : (-(29.0f / 60.0f) * (float)e + 30.0f);
    const float it = 1.0f / tao;
    float l0 = sl[0] * it, l1 = sl[1] * it, l2 = sl[2] * it, l3 = sl[3] * it;
    float mx = fmaxf(fmaxf(l0, l1), fmaxf(l2, l3));
    float e0 = expf(l0 - mx), e1 = expf(l1 - mx), e2 = expf(l2 - mx), e3 = expf(l3 - mx);
    float inv = 1.0f / (e0 + e1 + e2 + e3);
    float ga[4] = {e0 * inv, e1 * inv, e2 * inv, e3 * inv};

    float accW[16];
    #pragma unroll
    for (int m = 0; m < 16; m++) accW[m] = 0.f;
    #pragma unroll
    for (int k = 0; k < 4; k++) {
        __syncthreads();
        for (int i = tid; i < 4096; i += 256) {      // coalesced read of W[k] ([c][d] order)
            int c = i >> 6, dd = i & 63;
            wk[c * 65 + dd] = Wm[k * 4096 + i];
        }
        __syncthreads();
        #pragma unroll
        for (int m = 0; m < 16; m++) {
            int idx = m * 256 + tid;                 // idx = d*64 + c (transposed output order)
            int dd = idx >> 6, c = idx & 63;
            accW[m] = fmaf(ga[k], wk[c * 65 + dd], accW[m]);
        }
    }
    #pragma unroll
    for (int m = 0; m < 16; m++) WfT[n * 4096 + m * 256 + tid] = accW[m];  // coalesced
    if (tid < 64)
        bfv[n * 64 + tid] = ga[0] * bm[tid] + ga[1] * bm[64 + tid] +
                            ga[2] * bm[128 + tid] + ga[3] * bm[192 + tid];
    if (n == 0) {
        for (int j = tid; j < 1600; j += 256) {
            int s = shin[j];
            gi[j] = (s & 63) * 100 + (s >> 6);       // offset into xs[c'][tt][v'] (TT=4)
            mg[j] = tanhf(mask[j]) + 1.0f;
        }
    }
}

// ---------------- K3: y[n,t,v,d] = gather(x0)*mask @ Wf + bf ; bf16 store + BN stats ----------------
__global__ __launch_bounds__(256, 2) void k_main(
    const float* __restrict__ x0, const float* __restrict__ WfT,
    const float* __restrict__ bfv, const float* __restrict__ mgg,
    const int* __restrict__ gig, __hip_bfloat16* __restrict__ y,
    float* __restrict__ ssumg, float* __restrict__ ssqg)
{
    __shared__ float xs[6400];        // x0[n, c', t0+ts .. +3, v']  = [c'][tt][v']
    __shared__ float xg[4][1600];     // per-wave gathered+masked row (wave-private)
    const int tid = threadIdx.x;
    const int w = tid >> 6, ln = tid & 63;
    const int n = blockIdx.x >> 3;
    const int t0 = (blockIdx.x & 7) * 32;

    // per-lane Wf column d=ln: wfr[c] = Wf[c][ln] (WfT is [n][d][c], per-lane contiguous)
    float wfr[64];
    {
        const float4* wp = (const float4*)(WfT + (size_t)n * 4096 + ln * 64);
        #pragma unroll
        for (int q = 0; q < 16; q++) {
            float4 f = wp[q];
            wfr[4*q+0] = f.x; wfr[4*q+1] = f.y; wfr[4*q+2] = f.z; wfr[4*q+3] = f.w;
        }
    }
    const float bfl = bfv[n * 64 + ln];
    int giv[25]; float mgv[25];
    #pragma unroll
    for (int i = 0; i < 25; i++) { giv[i] = gig[i * 64 + ln]; mgv[i] = mgg[i * 64 + ln]; }
    float ssum[25], ssq[25];
    #pragma unroll
    for (int v = 0; v < 25; v++) { ssum[v] = 0.f; ssq[v] = 0.f; }

    const float* xn = x0 + (size_t)n * CTV;
    for (int ts = 0; ts < 32; ts += 4) {
        __syncthreads();
        {   // stage 4 t's: 64 runs of 100 contiguous floats (400B), float4 loads
            const float4* src = (const float4*)(xn + (t0 + ts) * 25);
            float4* dst = (float4*)xs;
            for (int i = tid; i < 1600; i += 256) {
                int cp = i / 25, r = i - cp * 25;
                dst[i] = src[cp * 1600 + r];
            }
        }
        __syncthreads();
        const int t = t0 + ts + w;                 // each wave owns one t
        float* xgw = xg[w];
        const int tof = w * 25;
        #pragma unroll
        for (int i = 0; i < 25; i++)               // gather + mask (wave-private, no barrier)
            xgw[i * 64 + ln] = xs[giv[i] + tof] * mgv[i];
        float acc[25];
        #pragma unroll
        for (int v = 0; v < 25; v++) acc[v] = 0.f;
        #pragma unroll
        for (int q = 0; q < 16; q++) {             // broadcast ds_read_b128: 1 per 4 FMAs
            #pragma unroll
            for (int v = 0; v < 25; v++) {
                float4 f = ((const float4*)(xgw + v * 64))[q];
                acc[v] = fmaf(f.x, wfr[4*q+0], acc[v]);
                acc[v] = fmaf(f.y, wfr[4*q+1], acc[v]);
                acc[v] = fmaf(f.z, wfr[4*q+2], acc[v]);
                acc[v] = fmaf(f.w, wfr[4*q+3], acc[v]);
            }
        }
        __hip_bfloat16* yb = y + (size_t)(n * T_ + t) * 1600 + ln;
        #pragma unroll
        for (int v = 0; v < 25; v++) {
            float val = acc[v] + bfl;
            ssum[v] += val;
            ssq[v] = fmaf(val, val, ssq[v]);
            yb[v * 64] = __float2bfloat16(val);
        }
    }
    #pragma unroll
    for (int v = 0; v < 25; v++) {                 // feature = v*64 + d(=lane): all distinct addrs
        atomicAdd(&ssumg[v * 64 + ln], ssum[v]);
        atomicAdd(&ssqg[v * 64 + ln], ssq[v]);
    }
}

// ---------------- K4: finalize BN -> A2/B2/S2 in output (do*25+vo) order ----------------
__global__ __launch_bounds__(256) void k_bn(
    const float* __restrict__ ssum, const float* __restrict__ ssq,
    const float* __restrict__ gamma, const float* __restrict__ beta,
    const int* __restrict__ shout,
    float* __restrict__ A2, float* __restrict__ B2, int* __restrict__ S2)
{
    int j = blockIdx.x * 256 + threadIdx.x;        // z-feature j = vo*64 + do
    if (j >= 1600) return;
    int src = shout[j];                            // y-feature
    const float invn = 1.0f / 32768.0f;
    float mu = ssum[src] * invn;
    float var = ssq[src] * invn - mu * mu;
    float rstd = rsqrtf(var + 1e-5f);
    float a = gamma[j] * rstd;
    float bb = beta[j] - mu * a;
    int dd = j & 63, vo = j >> 6;
    int jo = dd * 25 + vo;                         // output-layout order
    A2[jo] = a; B2[jo] = bb; S2[jo] = src;
}

// ---------------- K5: gather(y) -> BN apply -> +x0 -> relu -> out[n,d,t,v] ----------------
__global__ __launch_bounds__(256) void k_out(
    const __hip_bfloat16* __restrict__ y, const float* __restrict__ x0,
    const float* __restrict__ A2, const float* __restrict__ B2,
    const int* __restrict__ S2, float* __restrict__ out)
{
    __shared__ __align__(16) unsigned short ys[16 * 1600];  // 16 t-rows of bf16 y
    __shared__ float a_s[1600], b_s[1600];
    __shared__ int s_s[1600];
    const int tid = threadIdx.x;
    const int n = blockIdx.x >> 4;
    const int t0 = (blockIdx.x & 15) * 16;
    const uint4* ysrc = (const uint4*)((const unsigned short*)y + (size_t)(n * T_ + t0) * 1600);
    uint4* ydst = (uint4*)ys;
    for (int i = tid; i < 3200; i += 256) ydst[i] = ysrc[i];          // 51.2KB contiguous
    for (int i = tid; i < 1600; i += 256) { a_s[i] = A2[i]; b_s[i] = B2[i]; s_s[i] = S2[i]; }
    __syncthreads();
    const float* xb = x0 + (size_t)n * CTV;
    float* ob = out + (size_t)n * CTV;
    for (int t = 0; t < 16; t++) {
        const int tg = t0 + t;
        const int tbase = t * 1600;
        for (int jo = tid; jo < 1600; jo += 256) {                    // jo = do*25+vo: coalesced out
            int dd = jo / 25;
            int vo = jo - dd * 25;
            unsigned short raw = ys[tbase + s_s[jo]];
            float val = __uint_as_float(((unsigned)raw) << 16);
            int addr = dd * TV + tg * 25 + vo;
            float o = fmaf(val, a_s[jo], b_s[jo]) + xb[addr];
            ob[addr] = fmaxf(o, 0.f);
        }
    }
}

extern "C" void kernel_launch(void* const* d_in, const int* in_sizes, int n_in,
                              void* d_out, int out_size, void* d_ws, size_t ws_size,
                              hipStream_t stream) {
    const float* x0    = (const float*)d_in[0];
    const int*   ep    = (const int*)  d_in[1];
    const float* fc1w  = (const float*)d_in[2];
    const float* fc1b  = (const float*)d_in[3];
    const float* fc2w  = (const float*)d_in[4];
    const float* fc2b  = (const float*)d_in[5];
    const float* Wm    = (const float*)d_in[6];
    const float* bm    = (const float*)d_in[7];
    const float* mask  = (const float*)d_in[8];
    const float* gamma = (const float*)d_in[9];
    const float* beta  = (const float*)d_in[10];
    const int*   shin  = (const int*)  d_in[11];
    const int*   shout = (const int*)  d_in[12];
    float* out = (float*)d_out;

    float* wsf    = (float*)d_ws;
    float* pooled = wsf;                    // 8192
    float* WfT    = wsf + 8192;             // 524288
    float* bfv    = wsf + 532480;           // 8192
    float* mg     = wsf + 540672;           // 1600
    int*   gi     = (int*)(wsf + 542272);   // 1600
    float* ssum   = wsf + 543872;           // 1600
    float* ssq    = wsf + 545472;           // 1600
    float* A2     = wsf + 547072;           // 1600
    float* B2     = wsf + 548672;           // 1600
    int*   S2     = (int*)(wsf + 550272);   // 1600
    __hip_bfloat16* y = (__hip_bfloat16*)(wsf + 551872);  // 52,428,800 bf16 (~105MB)

    hipMemsetAsync(ssum, 0, 3200 * sizeof(float), stream);   // zero ssum+ssq (contiguous)
    k_pool<<<N_ * C_, 256, 0, stream>>>(x0, pooled);
    k_se<<<N_, 256, 0, stream>>>(pooled, fc1w, fc1b, fc2w, fc2b, Wm, bm, mask,
                                 shin, ep, WfT, bfv, mg, gi);
    k_main<<<N_ * 8, 256, 0, stream>>>(x0, WfT, bfv, mg, gi, y, ssum, ssq);
    k_bn<<<7, 256, 0, stream>>>(ssum, ssq, gamma, beta, shout, A2, B2, S2);
    k_out<<<N_ * 16, 256, 0, stream>>>(y, x0, A2, B2, S2, out);
}

// Round 2
// 756.338 us; speedup vs baseline: 1.6563x; 1.6563x over previous
//
#include <hip/hip_runtime.h>
#include <hip/hip_bf16.h>
#include <math.h>

#define N_   128
#define C_   64
#define T_   256
#define V_   25
#define D_   64
#define CTV  409600   // C*T*V
#define TV   6400     // T*V

typedef __attribute__((ext_vector_type(8))) short short8;
typedef __attribute__((ext_vector_type(4))) short short4v;
typedef __attribute__((ext_vector_type(4))) float f32x4;

__device__ inline unsigned short f2b(float f) {
    __hip_bfloat16 h = __float2bfloat16(f);
    return *(unsigned short*)&h;
}
__device__ inline float b2f(unsigned short u) {
    return __uint_as_float(((unsigned)u) << 16);
}

// ---------------- K1: pooled[n*64+c] = mean over (t,v) ----------------
__global__ __launch_bounds__(256) void k_pool(const float* __restrict__ x0,
                                              float* __restrict__ pooled) {
    const int bid = blockIdx.x;            // n*64 + c  (plane of 6400 contiguous floats)
    const int tid = threadIdx.x;
    const float4* base = (const float4*)(x0 + (size_t)bid * TV);
    float s = 0.f;
    for (int i = tid; i < 1600; i += 256) {
        float4 f = base[i];
        s += (f.x + f.y) + (f.z + f.w);
    }
    #pragma unroll
    for (int off = 32; off > 0; off >>= 1) s += __shfl_down(s, off);
    __shared__ float red[4];
    if ((tid & 63) == 0) red[tid >> 6] = s;
    __syncthreads();
    if (tid == 0) pooled[bid] = (red[0] + red[1] + red[2] + red[3]) * (1.0f / TV);
}

// ---------------- K2: SE gate -> Wfb (bf16, B-frag order), bfv; gimg precompute ----------------
// Wfb[n] flat index e = ((w*2+s)*64 + lane)*8 + j  <->  B[c = s*32 + (lane>>4)*8 + j][d = w*16 + (lane&15)]
__global__ __launch_bounds__(256) void k_se(
    const float* __restrict__ pooled, const float* __restrict__ fc1w,
    const float* __restrict__ fc1b,  const float* __restrict__ fc2w,
    const float* __restrict__ fc2b,  const float* __restrict__ Wm,
    const float* __restrict__ bm,    const float* __restrict__ mask,
    const int* __restrict__ shin,    const int* __restrict__ ep,
    unsigned short* __restrict__ Wfb, float* __restrict__ bfv,
    unsigned* __restrict__ gimg)
{
    __shared__ float sp[64], sh[16], sl[4];
    __shared__ float wk[64 * 65];          // W[k] staged [c][d] padded (+1)
    const int tid = threadIdx.x, n = blockIdx.x;
    if (tid < 64) sp[tid] = pooled[n * 64 + tid];
    __syncthreads();
    if (tid < 16) {
        float s = fc1b[tid];
        #pragma unroll
        for (int c = 0; c < 64; c++) s = fmaf(sp[c], fc1w[tid * 64 + c], s);
        sh[tid] = fmaxf(s, 0.f);
    }
    __syncthreads();
    if (tid < 4) {
        float s = fc2b[tid];
        #pragma unroll
        for (int j = 0; j < 16; j++) s = fmaf(sh[j], fc2w[tid * 16 + j], s);
        sl[tid] = s;
    }
    __syncthreads();
    const int e = ep[0];
    const float tao = (e >= 60) ? 1.0f : (-(29.0f / 60.0f) * (float)e + 30.0f);
    const float it = 1.0f / tao;
    float l0 = sl[0] * it, l1 = sl[1] * it, l2 = sl[2] * it, l3 = sl[3] * it;
    float mx = fmaxf(fmaxf(l0, l1), fmaxf(l2, l3));
    float e0 = expf(l0 - mx), e1 = expf(l1 - mx), e2 = expf(l2 - mx), e3 = expf(l3 - mx);
    float inv = 1.0f / (e0 + e1 + e2 + e3);
    float ga[4] = {e0 * inv, e1 * inv, e2 * inv, e3 * inv};

    float accW[16];
    #pragma unroll
    for (int m = 0; m < 16; m++) accW[m] = 0.f;
    #pragma unroll
    for (int k = 0; k < 4; k++) {
        __syncthreads();
        for (int i = tid; i < 4096; i += 256)       // coalesced read of W[k] ([c][d])
            wk[(i >> 6) * 65 + (i & 63)] = Wm[k * 4096 + i];
        __syncthreads();
        #pragma unroll
        for (int m = 0; m < 16; m++) {
            int o = m * 256 + tid;                   // frag-order flat index
            int w  = o >> 10, s = (o >> 9) & 1;
            int ln = (o >> 3) & 63, j = o & 7;
            int c  = s * 32 + (ln >> 4) * 8 + j;
            int d  = w * 16 + (ln & 15);
            accW[m] = fmaf(ga[k], wk[c * 65 + d], accW[m]);
        }
    }
    #pragma unroll
    for (int m = 0; m < 16; m++)
        Wfb[(size_t)n * 4096 + m * 256 + tid] = f2b(accW[m]);   // coalesced shorts
    if (tid < 64)
        bfv[n * 64 + tid] = ga[0] * bm[tid] + ga[1] * bm[64 + tid] +
                            ga[2] * bm[128 + tid] + ga[3] * bm[192 + tid];
    if (n == 0) {
        for (int j = tid; j < 1600; j += 256) {     // j = v*64 + c
            int s = shin[j];
            unsigned off = (unsigned)((s & 63) * 100 + (s >> 6));  // xs elem offset (t=0)
            unsigned mgb = (unsigned)f2b(tanhf(mask[j]) + 1.0f);
            gimg[j] = (off << 16) | mgb;
        }
    }
}

// ---------------- K3: MFMA main: y = gather(x0)*mg @ Wf + bf (bf16), + BN stats ----------------
// Block: one n, 16 t's (4 sub-chunks of 4). Wave w owns N-tile w (d in [16w,16w+16)).
// A-tile rows: rho = (v>>2)*16 + t_local*4 + (v&3)  -> C-tile: v = 4*tile + reg (compile-time).
__global__ __launch_bounds__(256, 4) void k_main(
    const float* __restrict__ x0, const unsigned short* __restrict__ Wfb,
    const float* __restrict__ bfv, const unsigned* __restrict__ gimg,
    __hip_bfloat16* __restrict__ y, float* __restrict__ sn)
{
    __shared__ unsigned short xs[6400];    // x0 slab bf16: [c'][t*25+v']  (4 t's)
    __shared__ unsigned short At[7616];    // A-tile: 112 rows x 68 (stride 68 kills conflicts)
    __shared__ unsigned gimgS[1600];       // packed (srcOff<<16)|bf16(mg)

    const int tid = threadIdx.x;
    const int w = tid >> 6, l = tid & 63, q = l >> 4, m = l & 15;
    const int n = blockIdx.x >> 4;
    const int tbase = (blockIdx.x & 15) * 16;

    // B fragments (held whole kernel) + bias
    short8 bf0 = *(const short8*)(Wfb + (size_t)n * 4096 + (w * 2 + 0) * 512 + l * 8);
    short8 bf1 = *(const short8*)(Wfb + (size_t)n * 4096 + (w * 2 + 1) * 512 + l * 8);
    const int d = w * 16 + m;
    const float bfl = bfv[n * 64 + d];

    for (int i = tid; i < 1600; i += 256) gimgS[i] = gimg[i];
    // zero the 12 pad rows (v = 25..27 image): rho = 96 + t*4 + vr, vr in 1..3
    for (int i = tid; i < 408; i += 256) {
        int rr = i / 34, wo = i - rr * 34;
        int t = rr / 3, vr = rr - t * 3 + 1;
        ((unsigned*)At)[(96 + t * 4 + vr) * 34 + wo] = 0u;
    }

    float ss[25], sq[25];
    #pragma unroll
    for (int v = 0; v < 25; v++) { ss[v] = 0.f; sq[v] = 0.f; }

    for (int sub = 0; sub < 4; sub++) {
        const int t0 = tbase + sub * 4;
        __syncthreads();   // prev iter's At fully consumed
        {   // stage x0 slab -> bf16 xs : per c, 100 contiguous floats (25 float4)
            const float4* src = (const float4*)x0;
            const int fb = n * 102400 + (t0 * 25) / 4;   // t0 % 4 == 0
            for (int i = tid; i < 1600; i += 256) {
                int c = i / 25, r = i - c * 25;
                float4 f = src[fb + c * 1600 + r];
                unsigned lo = ((unsigned)f2b(f.y) << 16) | f2b(f.x);
                unsigned hi = ((unsigned)f2b(f.w) << 16) | f2b(f.z);
                *(unsigned*)&xs[c * 100 + r * 4]     = lo;
                *(unsigned*)&xs[c * 100 + r * 4 + 2] = hi;
            }
        }
        __syncthreads();
        // gather + mask -> At (bf16 pairs; lanes hit 32 distinct banks)
        for (int p = tid; p < 3200; p += 256) {
            int cp = p & 31, rv = p >> 5;          // rv = t*25 + v
            int t = rv / 25, v = rv - t * 25;
            int c = cp * 2;
            unsigned g0 = gimgS[v * 64 + c], g1 = gimgS[v * 64 + c + 1];
            float v0 = b2f(xs[(g0 >> 16) + t * 25]) * b2f((unsigned short)(g0 & 0xffff));
            float v1 = b2f(xs[(g1 >> 16) + t * 25]) * b2f((unsigned short)(g1 & 0xffff));
            int rho = (v >> 2) * 16 + t * 4 + (v & 3);
            *(unsigned*)&At[rho * 68 + c] = ((unsigned)f2b(v1) << 16) | f2b(v0);
        }
        __syncthreads();
        // MFMA: 7 M-tiles x 2 k-steps; epilogue per tile
        #pragma unroll
        for (int tau = 0; tau < 7; tau++) {
            const unsigned short* Ab = At + (tau * 16 + m) * 68 + q * 8;
            short4v a0l = *(const short4v*)(Ab);
            short4v a0h = *(const short4v*)(Ab + 4);
            short4v a1l = *(const short4v*)(Ab + 32);
            short4v a1h = *(const short4v*)(Ab + 36);
            short8 a0 = {a0l[0],a0l[1],a0l[2],a0l[3],a0h[0],a0h[1],a0h[2],a0h[3]};
            short8 a1 = {a1l[0],a1l[1],a1l[2],a1l[3],a1h[0],a1h[1],a1h[2],a1h[3]};
            f32x4 acc = {0.f, 0.f, 0.f, 0.f};
            acc = __builtin_amdgcn_mfma_f32_16x16x32_bf16(a0, bf0, acc, 0, 0, 0);
            acc = __builtin_amdgcn_mfma_f32_16x16x32_bf16(a1, bf1, acc, 0, 0, 0);
            const int t = t0 + q;                  // C row = q*4 + r -> t = q, vr = r
            __hip_bfloat16* yb = y + ((size_t)(n * T_ + t) * 25) * 64 + d;
            #pragma unroll
            for (int r = 0; r < 4; r++) {
                const int v = tau * 4 + r;
                if (v < 25) {
                    float val = acc[r] + bfl;
                    yb[v * 64] = __float2bfloat16(val);
                    ss[v] += val;
                    sq[v] = fmaf(val, val, sq[v]);
                }
            }
        }
    }
    // stats: reduce over q (4 lanes share same d & v-set), then 1 atomic/feature
    #pragma unroll
    for (int v = 0; v < 25; v++) {
        ss[v] += __shfl_xor(ss[v], 16); ss[v] += __shfl_xor(ss[v], 32);
        sq[v] += __shfl_xor(sq[v], 16); sq[v] += __shfl_xor(sq[v], 32);
    }
    if (q == 0) {
        float* sb = sn + (size_t)n * 3200;
        #pragma unroll
        for (int v = 0; v < 25; v++) {
            atomicAdd(&sb[v * 64 + d], ss[v]);
            atomicAdd(&sb[1600 + v * 64 + d], sq[v]);
        }
    }
}

// ---------------- K4: finalize BN -> A2/B2/S2 in output (do*25+vo) order ----------------
__global__ __launch_bounds__(256) void k_bn(
    const float* __restrict__ sn,
    const float* __restrict__ gamma, const float* __restrict__ beta,
    const int* __restrict__ shout,
    float* __restrict__ A2, float* __restrict__ B2, int* __restrict__ S2)
{
    int j = blockIdx.x * 256 + threadIdx.x;        // z-feature j = vo*64 + do
    if (j >= 1600) return;
    int src = shout[j];                            // y-feature
    float s = 0.f, qq = 0.f;
    for (int n = 0; n < 128; n++) {
        s  += sn[(size_t)n * 3200 + src];
        qq += sn[(size_t)n * 3200 + 1600 + src];
    }
    const float invn = 1.0f / 32768.0f;
    float mu = s * invn;
    float var = qq * invn - mu * mu;
    float rstd = rsqrtf(var + 1e-5f);
    float a = gamma[j] * rstd;
    float bb = beta[j] - mu * a;
    int dd = j & 63, vo = j >> 6;
    int jo = dd * 25 + vo;                         // output-layout order
    A2[jo] = a; B2[jo] = bb; S2[jo] = src;
}

// ---------------- K5: gather(y) -> BN apply -> +x0 -> relu -> out[n,d,t,v] ----------------
__global__ __launch_bounds__(256) void k_out(
    const __hip_bfloat16* __restrict__ y, const float* __restrict__ x0,
    const float* __restrict__ A2, const float* __restrict__ B2,
    const int* __restrict__ S2, float* __restrict__ out)
{
    __shared__ __align__(16) unsigned short ys[8 * 1600];   // 8 t-rows of bf16 y (25.6 KB)
    __shared__ float a_s[1600], b_s[1600];
    __shared__ int s_s[1600];
    const int tid = threadIdx.x;
    const int n = blockIdx.x >> 5;
    const int t0 = (blockIdx.x & 31) * 8;
    const uint4* ysrc = (const uint4*)((const unsigned short*)y + (size_t)(n * T_ + t0) * 1600);
    uint4* ydst = (uint4*)ys;
    for (int i = tid; i < 1600; i += 256) ydst[i] = ysrc[i];
    for (int i = tid; i < 1600; i += 256) { a_s[i] = A2[i]; b_s[i] = B2[i]; s_s[i] = S2[i]; }
    __syncthreads();
    const float* xb = x0 + (size_t)n * CTV;
    float* ob = out + (size_t)n * CTV;
    for (int t = 0; t < 8; t++) {
        const int tg = t0 + t;
        const int tbase = t * 1600;
        for (int jo = tid; jo < 1600; jo += 256) {          // jo = do*25+vo: coalesced out
            int dd = jo / 25;
            int vo = jo - dd * 25;
            float val = b2f(ys[tbase + s_s[jo]]);
            int addr = dd * TV + tg * 25 + vo;
            float o = fmaf(val, a_s[jo], b_s[jo]) + xb[addr];
            ob[addr] = fmaxf(o, 0.f);
        }
    }
}

extern "C" void kernel_launch(void* const* d_in, const int* in_sizes, int n_in,
                              void* d_out, int out_size, void* d_ws, size_t ws_size,
                              hipStream_t stream) {
    const float* x0    = (const float*)d_in[0];
    const int*   ep    = (const int*)  d_in[1];
    const float* fc1w  = (const float*)d_in[2];
    const float* fc1b  = (const float*)d_in[3];
    const float* fc2w  = (const float*)d_in[4];
    const float* fc2b  = (const float*)d_in[5];
    const float* Wm    = (const float*)d_in[6];
    const float* bm    = (const float*)d_in[7];
    const float* mask  = (const float*)d_in[8];
    const float* gamma = (const float*)d_in[9];
    const float* beta  = (const float*)d_in[10];
    const int*   shin  = (const int*)  d_in[11];
    const int*   shout = (const int*)  d_in[12];
    float* out = (float*)d_out;

    float* wsf = (float*)d_ws;
    float*          pooled = wsf;                        // 8192
    float*          bfv    = wsf + 8192;                 // 8192
    unsigned*       gimg   = (unsigned*)(wsf + 16384);   // 1600
    float*          A2     = wsf + 17984;                // 1600
    float*          B2     = wsf + 19584;                // 1600
    int*            S2     = (int*)(wsf + 21184);        // 1600
    unsigned short* Wfb    = (unsigned short*)(wsf + 22784);   // 524288 bf16 (262144 words)
    float*          sn     = wsf + 284928;               // 128*3200 = 409600
    __hip_bfloat16* y      = (__hip_bfloat16*)(wsf + 694528);  // 52,428,800 bf16

    hipMemsetAsync(sn, 0, 409600 * sizeof(float), stream);
    k_pool<<<N_ * C_, 256, 0, stream>>>(x0, pooled);
    k_se<<<N_, 256, 0, stream>>>(pooled, fc1w, fc1b, fc2w, fc2b, Wm, bm, mask,
                                 shin, ep, Wfb, bfv, gimg);
    k_main<<<N_ * 16, 256, 0, stream>>>(x0, Wfb, bfv, gimg, y, sn);
    k_bn<<<7, 256, 0, stream>>>(sn, gamma, beta, shout, A2, B2, S2);
    k_out<<<N_ * 32, 256, 0, stream>>>(y, x0, A2, B2, S2, out);
}

// Round 4
// 652.672 us; speedup vs baseline: 1.9193x; 1.1588x over previous
//
#include <hip/hip_runtime.h>
#include <hip/hip_bf16.h>
#include <math.h>

#define N_   128
#define C_   64
#define T_   256
#define V_   25
#define D_   64
#define CTV  409600   // C*T*V
#define TV   6400     // T*V

typedef __attribute__((ext_vector_type(8))) short short8;
typedef __attribute__((ext_vector_type(4))) short short4v;
typedef __attribute__((ext_vector_type(4))) float f32x4;

__device__ inline unsigned short f2b(float f) {
    __hip_bfloat16 h = __float2bfloat16(f);
    return *(unsigned short*)&h;
}
__device__ inline float b2f(unsigned short u) {
    return __uint_as_float(((unsigned)u) << 16);
}

// ---------------- K1: pooled[n*64+c] = mean over (t,v) ----------------
__global__ __launch_bounds__(256) void k_pool(const float* __restrict__ x0,
                                              float* __restrict__ pooled) {
    const int bid = blockIdx.x;            // n*64 + c  (plane of 6400 contiguous floats)
    const int tid = threadIdx.x;
    const float4* base = (const float4*)(x0 + (size_t)bid * TV);
    float s = 0.f;
    for (int i = tid; i < 1600; i += 256) {
        float4 f = base[i];
        s += (f.x + f.y) + (f.z + f.w);
    }
    #pragma unroll
    for (int off = 32; off > 0; off >>= 1) s += __shfl_down(s, off);
    __shared__ float red[4];
    if ((tid & 63) == 0) red[tid >> 6] = s;
    __syncthreads();
    if (tid == 0) pooled[bid] = (red[0] + red[1] + red[2] + red[3]) * (1.0f / TV);
}

// ---------------- K2: SE gate -> Wfb (bf16, B-frag order), bfv; gimg precompute ----------------
// Wfb[n] flat index e = ((w*2+s)*64 + lane)*8 + j  <->  B[c = s*32 + (lane>>4)*8 + j][d = w*16 + (lane&15)]
__global__ __launch_bounds__(256) void k_se(
    const float* __restrict__ pooled, const float* __restrict__ fc1w,
    const float* __restrict__ fc1b,  const float* __restrict__ fc2w,
    const float* __restrict__ fc2b,  const float* __restrict__ Wm,
    const float* __restrict__ bm,    const float* __restrict__ mask,
    const int* __restrict__ shin,    const int* __restrict__ ep,
    unsigned short* __restrict__ Wfb, float* __restrict__ bfv,
    unsigned* __restrict__ gimg)
{
    __shared__ float sp[64], sh[16], sl[4];
    __shared__ float wk[64 * 65];          // W[k] staged [c][d] padded (+1)
    const int tid = threadIdx.x, n = blockIdx.x;
    if (tid < 64) sp[tid] = pooled[n * 64 + tid];
    __syncthreads();
    if (tid < 16) {
        float s = fc1b[tid];
        #pragma unroll
        for (int c = 0; c < 64; c++) s = fmaf(sp[c], fc1w[tid * 64 + c], s);
        sh[tid] = fmaxf(s, 0.f);
    }
    __syncthreads();
    if (tid < 4) {
        float s = fc2b[tid];
        #pragma unroll
        for (int j = 0; j < 16; j++) s = fmaf(sh[j], fc2w[tid * 16 + j], s);
        sl[tid] = s;
    }
    __syncthreads();
    const int e = ep[0];
    const float tao = (e >= 60) ? 1.0f : (-(29.0f / 60.0f) * (float)e + 30.0f);
    const float it = 1.0f / tao;
    float l0 = sl[0] * it, l1 = sl[1] * it, l2 = sl[2] * it, l3 = sl[3] * it;
    float mx = fmaxf(fmaxf(l0, l1), fmaxf(l2, l3));
    float e0 = expf(l0 - mx), e1 = expf(l1 - mx), e2 = expf(l2 - mx), e3 = expf(l3 - mx);
    float inv = 1.0f / (e0 + e1 + e2 + e3);
    float ga[4] = {e0 * inv, e1 * inv, e2 * inv, e3 * inv};

    float accW[16];
    #pragma unroll
    for (int m = 0; m < 16; m++) accW[m] = 0.f;
    #pragma unroll
    for (int k = 0; k < 4; k++) {
        __syncthreads();
        for (int i = tid; i < 4096; i += 256)       // coalesced read of W[k] ([c][d])
            wk[(i >> 6) * 65 + (i & 63)] = Wm[k * 4096 + i];
        __syncthreads();
        #pragma unroll
        for (int m = 0; m < 16; m++) {
            int o = m * 256 + tid;                   // frag-order flat index
            int w  = o >> 10, s = (o >> 9) & 1;
            int ln = (o >> 3) & 63, j = o & 7;
            int c  = s * 32 + (ln >> 4) * 8 + j;
            int d  = w * 16 + (ln & 15);
            accW[m] = fmaf(ga[k], wk[c * 65 + d], accW[m]);
        }
    }
    #pragma unroll
    for (int m = 0; m < 16; m++)
        Wfb[(size_t)n * 4096 + m * 256 + tid] = f2b(accW[m]);   // coalesced shorts
    if (tid < 64)
        bfv[n * 64 + tid] = ga[0] * bm[tid] + ga[1] * bm[64 + tid] +
                            ga[2] * bm[128 + tid] + ga[3] * bm[192 + tid];
    if (n == 0) {
        for (int j = tid; j < 1600; j += 256) {     // j = v*64 + c
            int s = shin[j];
            unsigned off = (unsigned)((s & 63) * 100 + (s >> 6));  // xs elem offset (t=0)
            unsigned mgb = (unsigned)f2b(tanhf(mask[j]) + 1.0f);
            gimg[j] = (off << 16) | mgb;
        }
    }
}

// ---------------- K3: MFMA main: y = gather(x0)*mg @ Wf + bf (bf16), + BN stats ----------------
// Block: one n, 16 t's (4 sub-chunks of 4). Wave w owns N-tile w (d in [16w,16w+16)).
// A-tile rows: rho = (v>>2)*16 + t_local*4 + (v&3)  -> C-tile: v = 4*tile + reg (compile-time).
__global__ __launch_bounds__(256, 4) void k_main(
    const float* __restrict__ x0, const unsigned short* __restrict__ Wfb,
    const float* __restrict__ bfv, const unsigned* __restrict__ gimg,
    __hip_bfloat16* __restrict__ y, float* __restrict__ sn)
{
    __shared__ unsigned short xs[6400];    // x0 slab bf16: [c'][t*25+v']  (4 t's)
    __shared__ unsigned short At[7616];    // A-tile: 112 rows x 68 (stride 68 kills conflicts)
    __shared__ unsigned gimgS[1600];       // packed (srcOff<<16)|bf16(mg)

    const int tid = threadIdx.x;
    const int w = tid >> 6, l = tid & 63, q = l >> 4, m = l & 15;
    const int n = blockIdx.x >> 4;
    const int tbase = (blockIdx.x & 15) * 16;

    // B fragments (held whole kernel) + bias
    short8 bf0 = *(const short8*)(Wfb + (size_t)n * 4096 + (w * 2 + 0) * 512 + l * 8);
    short8 bf1 = *(const short8*)(Wfb + (size_t)n * 4096 + (w * 2 + 1) * 512 + l * 8);
    const int d = w * 16 + m;
    const float bfl = bfv[n * 64 + d];

    for (int i = tid; i < 1600; i += 256) gimgS[i] = gimg[i];
    // zero the 12 pad rows (v = 25..27 image): rho = 96 + t*4 + vr, vr in 1..3
    for (int i = tid; i < 408; i += 256) {
        int rr = i / 34, wo = i - rr * 34;
        int t = rr / 3, vr = rr - t * 3 + 1;
        ((unsigned*)At)[(96 + t * 4 + vr) * 34 + wo] = 0u;
    }

    float ss[25], sq[25];
    #pragma unroll
    for (int v = 0; v < 25; v++) { ss[v] = 0.f; sq[v] = 0.f; }

    for (int sub = 0; sub < 4; sub++) {
        const int t0 = tbase + sub * 4;
        __syncthreads();   // prev iter's At fully consumed
        {   // stage x0 slab -> bf16 xs : per c, 100 contiguous floats (25 float4)
            const float4* src = (const float4*)x0;
            const int fb = n * 102400 + (t0 * 25) / 4;   // t0 % 4 == 0
            for (int i = tid; i < 1600; i += 256) {
                int c = i / 25, r = i - c * 25;
                float4 f = src[fb + c * 1600 + r];
                unsigned lo = ((unsigned)f2b(f.y) << 16) | f2b(f.x);
                unsigned hi = ((unsigned)f2b(f.w) << 16) | f2b(f.z);
                *(unsigned*)&xs[c * 100 + r * 4]     = lo;
                *(unsigned*)&xs[c * 100 + r * 4 + 2] = hi;
            }
        }
        __syncthreads();
        // gather + mask -> At (bf16 pairs; lanes hit 32 distinct banks)
        for (int p = tid; p < 3200; p += 256) {
            int cp = p & 31, rv = p >> 5;          // rv = t*25 + v
            int t = rv / 25, v = rv - t * 25;
            int c = cp * 2;
            unsigned g0 = gimgS[v * 64 + c], g1 = gimgS[v * 64 + c + 1];
            float v0 = b2f(xs[(g0 >> 16) + t * 25]) * b2f((unsigned short)(g0 & 0xffff));
            float v1 = b2f(xs[(g1 >> 16) + t * 25]) * b2f((unsigned short)(g1 & 0xffff));
            int rho = (v >> 2) * 16 + t * 4 + (v & 3);
            *(unsigned*)&At[rho * 68 + c] = ((unsigned)f2b(v1) << 16) | f2b(v0);
        }
        __syncthreads();
        // MFMA: 7 M-tiles x 2 k-steps; epilogue per tile
        #pragma unroll
        for (int tau = 0; tau < 7; tau++) {
            const unsigned short* Ab = At + (tau * 16 + m) * 68 + q * 8;
            short4v a0l = *(const short4v*)(Ab);
            short4v a0h = *(const short4v*)(Ab + 4);
            short4v a1l = *(const short4v*)(Ab + 32);
            short4v a1h = *(const short4v*)(Ab + 36);
            short8 a0 = {a0l[0],a0l[1],a0l[2],a0l[3],a0h[0],a0h[1],a0h[2],a0h[3]};
            short8 a1 = {a1l[0],a1l[1],a1l[2],a1l[3],a1h[0],a1h[1],a1h[2],a1h[3]};
            f32x4 acc = {0.f, 0.f, 0.f, 0.f};
            acc = __builtin_amdgcn_mfma_f32_16x16x32_bf16(a0, bf0, acc, 0, 0, 0);
            acc = __builtin_amdgcn_mfma_f32_16x16x32_bf16(a1, bf1, acc, 0, 0, 0);
            const int t = t0 + q;                  // C row = q*4 + r -> t = q, vr = r
            __hip_bfloat16* yb = y + ((size_t)(n * T_ + t) * 25) * 64 + d;
            #pragma unroll
            for (int r = 0; r < 4; r++) {
                const int v = tau * 4 + r;
                if (v < 25) {
                    float val = acc[r] + bfl;
                    yb[v * 64] = __float2bfloat16(val);
                    ss[v] += val;
                    sq[v] = fmaf(val, val, sq[v]);
                }
            }
        }
    }
    // stats: reduce over q (4 lanes share same d & v-set), then 1 atomic/feature
    #pragma unroll
    for (int v = 0; v < 25; v++) {
        ss[v] += __shfl_xor(ss[v], 16); ss[v] += __shfl_xor(ss[v], 32);
        sq[v] += __shfl_xor(sq[v], 16); sq[v] += __shfl_xor(sq[v], 32);
    }
    if (q == 0) {
        float* sb = sn + (size_t)n * 3200;
        #pragma unroll
        for (int v = 0; v < 25; v++) {
            atomicAdd(&sb[v * 64 + d], ss[v]);
            atomicAdd(&sb[1600 + v * 64 + d], sq[v]);
        }
    }
}

// ---------------- K4: finalize BN -> A2/B2 (jo=do*25+vo order), S2 = padded LDS offset vy*66+dy ----------------
__global__ __launch_bounds__(256) void k_bn(
    const float* __restrict__ sn,
    const float* __restrict__ gamma, const float* __restrict__ beta,
    const int* __restrict__ shout,
    float* __restrict__ A2, float* __restrict__ B2, int* __restrict__ S2)
{
    int j = blockIdx.x * 256 + threadIdx.x;        // z-feature j = vo*64 + do
    if (j >= 1600) return;
    int src = shout[j];                            // y-feature vy*64 + dy
    float s = 0.f, qq = 0.f;
    for (int n = 0; n < 128; n++) {
        s  += sn[(size_t)n * 3200 + src];
        qq += sn[(size_t)n * 3200 + 1600 + src];
    }
    const float invn = 1.0f / 32768.0f;
    float mu = s * invn;
    float var = qq * invn - mu * mu;
    float rstd = rsqrtf(var + 1e-5f);
    float a = gamma[j] * rstd;
    float bb = beta[j] - mu * a;
    int dd = j & 63, vo = j >> 6;
    int jo = dd * 25 + vo;                         // output-layout order
    A2[jo] = a; B2[jo] = bb;
    S2[jo] = (src >> 6) * 66 + (src & 63);         // offset into padded LDS y-slab row
}

// ---------------- K5: y -> BN apply -> +x0 -> relu -> out[n,d,t,v] (padded LDS, full-line writes) ----------------
__global__ __launch_bounds__(256) void k_out(
    const __hip_bfloat16* __restrict__ y, const float* __restrict__ x0,
    const float* __restrict__ A2, const float* __restrict__ B2,
    const int* __restrict__ S2, float* __restrict__ out)
{
    __shared__ __align__(16) unsigned short ys[8 * 1652];   // v-stride 66, t-stride 1652
    __shared__ float aS[1600], bS[1600];
    __shared__ int sS[1600];
    const int tid = threadIdx.x;
    const int n = blockIdx.x >> 5;
    const int t0 = (blockIdx.x & 31) * 8;
    const uint4* ysrc = (const uint4*)((const unsigned short*)y + (size_t)(n * T_ + t0) * 1600);
    for (int i = tid; i < 1600; i += 256) {        // stage y slab into padded LDS
        uint4 g = ysrc[i];
        int tl = i / 200, r8 = (i - tl * 200) * 8;
        int v = r8 >> 6, d0 = r8 & 63;
        unsigned* p = (unsigned*)ys + ((tl * 1652 + v * 66 + d0) >> 1);
        p[0] = g.x; p[1] = g.y; p[2] = g.z; p[3] = g.w;
    }
    for (int i = tid; i < 1600; i += 256) { aS[i] = A2[i]; bS[i] = B2[i]; sS[i] = S2[i]; }
    __syncthreads();
    const float* xb = x0 + (size_t)n * CTV + t0 * 25;
    float* ob = out + (size_t)n * CTV + t0 * 25;
    for (int o = tid; o < 12800; o += 256) {       // o = d*200 + tl*25 + vo
        int dd = o / 200, rem = o - dd * 200;
        int tl = rem / 25, vo = rem - tl * 25;
        int jo = dd * 25 + vo;
        float val = b2f(ys[tl * 1652 + sS[jo]]);
        int addr = dd * TV + rem;                  // contiguous per d-plane -> full lines
        float r = fmaf(val, aS[jo], bS[jo]) + xb[addr];
        ob[addr] = fmaxf(r, 0.f);
    }
}

extern "C" void kernel_launch(void* const* d_in, const int* in_sizes, int n_in,
                              void* d_out, int out_size, void* d_ws, size_t ws_size,
                              hipStream_t stream) {
    const float* x0    = (const float*)d_in[0];
    const int*   ep    = (const int*)  d_in[1];
    const float* fc1w  = (const float*)d_in[2];
    const float* fc1b  = (const float*)d_in[3];
    const float* fc2w  = (const float*)d_in[4];
    const float* fc2b  = (const float*)d_in[5];
    const float* Wm    = (const float*)d_in[6];
    const float* bm    = (const float*)d_in[7];
    const float* mask  = (const float*)d_in[8];
    const float* gamma = (const float*)d_in[9];
    const float* beta  = (const float*)d_in[10];
    const int*   shin  = (const int*)  d_in[11];
    const int*   shout = (const int*)  d_in[12];
    float* out = (float*)d_out;

    float* wsf = (float*)d_ws;
    float*          pooled = wsf;                        // 8192
    float*          bfv    = wsf + 8192;                 // 8192
    unsigned*       gimg   = (unsigned*)(wsf + 16384);   // 1600
    float*          A2     = wsf + 17984;                // 1600
    float*          B2     = wsf + 19584;                // 1600
    int*            S2     = (int*)(wsf + 21184);        // 1600
    unsigned short* Wfb    = (unsigned short*)(wsf + 22784);   // 524288 bf16 (262144 words)
    float*          sn     = wsf + 284928;               // 128*3200 = 409600
    __hip_bfloat16* y      = (__hip_bfloat16*)(wsf + 694528);  // 52,428,800 bf16

    hipMemsetAsync(sn, 0, 409600 * sizeof(float), stream);
    k_pool<<<N_ * C_, 256, 0, stream>>>(x0, pooled);
    k_se<<<N_, 256, 0, stream>>>(pooled, fc1w, fc1b, fc2w, fc2b, Wm, bm, mask,
                                 shin, ep, Wfb, bfv, gimg);
    k_main<<<N_ * 16, 256, 0, stream>>>(x0, Wfb, bfv, gimg, y, sn);
    k_bn<<<7, 256, 0, stream>>>(sn, gamma, beta, shout, A2, B2, S2);
    k_out<<<N_ * 32, 256, 0, stream>>>(y, x0, A2, B2, S2, out);
}